// Round 2
// baseline (932.599 us; speedup 1.0000x reference)
//
#include <hip/hip_runtime.h>
#include <float.h>

// Problem constants (match reference)
constexpr int H = 1024, W = 1024, C = 128, N_ITER = 8;
constexpr int TPB = 256;          // threads per block
constexpr int TILE = 32;          // 32x32 pixel tile per block
constexpr int PPT = 4;            // pixels (consecutive cols) per thread
constexpr int K = 32;             // atomic shards (contention depth 1024/K = 32)
constexpr int SLOTS = 2 * C;      // 256 accumulator slots
constexpr int NBLK = (H / TILE) * (W / TILE);   // 1024 blocks
constexpr int NCNT = 128;         // barrier counters per iteration (arrival depth 8)
constexpr int CNT_STRIDE = 16;    // ints between counters (64B) -> spread L2 channels

// Round-3 lesson: atomic-contention-bound -> 32-way sharding (kept).
//   (measured: depth-1024 same-address RMW ~= 43us -> ~100cy per same-address RMW.
//    This is also why the grid barrier below shards its arrival counters.)
// Round-4 lesson: O(C) dependent-LDS dedup chain -> all-pairs scan on 256
//   threads (kept). Bought the predicted ~2us/step.
// Round-5 (this round): per-step kernel work is only ~2-4us but each step cost
//   ~15-17us -> the residual is the 9 serialized dispatch boundaries (~10us
//   launch+drain each). Fuse everything into ONE persistent cooperative
//   kernel; iterations separated by a sharded device-scope barrier:
//   arrive = release-fetch_add on counter[bid&127] (depth 8 x ~100cy),
//   wait = lanes 0..127 acquire-spin each on one counter, then __syncthreads.
//   Per-iteration counters (no generation reuse). Heatmap/pixel setup now
//   loaded once instead of 8x; finalize folded into block 0.
__global__ __launch_bounds__(TPB) void kmeans_fused(
    const float* __restrict__ cur0,        // [SLOTS] input clusters
    const float* __restrict__ heatmap,     // [H,W]
    float* __restrict__ shards,            // [N_ITER][K][SLOTS] (pre-zeroed)
    int*   __restrict__ barCnt,            // [N_ITER][NCNT*CNT_STRIDE] (pre-zeroed)
    float* __restrict__ out)               // [SLOTS]
{
    __shared__ float2 cls[C];              // aliased as float[SLOTS]
    __shared__ float2 cand[C];
    __shared__ int    candIdx[C];
    __shared__ float  waveMin[2];
    __shared__ int    waveCnt[2];
    __shared__ float  acc[SLOTS];          // SLOTS == 256 == TPB
    __shared__ unsigned char dupf[C];      // 1 = has a lower-indexed twin

    const int tid   = threadIdx.x;
    const int bid   = blockIdx.x;
    const int tileR = (bid >> 5) * TILE;
    const int tileC = (bid & 31) * TILE;

    // ---- one-time pixel setup (was per-dispatch; now amortized over 8 iters) ----
    const int   rowIn = tid >> 3;                         // 0..31
    const float fr    = (float)(tileR + rowIn);
    const int   col0  = tileC + (tid & 7) * PPT;
    const float4 h4   = *(const float4*)(heatmap + (size_t)(tileR + rowIn) * W + col0);
    float hval[PPT] = { h4.x, h4.y, h4.z, h4.w };
    float colf[PPT];
#pragma unroll
    for (int p = 0; p < PPT; ++p) colf[p] = (float)(col0 + p);

    for (int it = 0; it < N_ITER; ++it) {
        float* outS = shards + (size_t)it * K * SLOTS;

        // ---- phase 0: materialize current cluster coords into LDS ----
        float coord;
        if (it == 0) {
            coord = cur0[tid];
        } else {
            const float* prevS = shards + (size_t)(it - 1) * K * SLOTS;
            float s = 0.0f;
#pragma unroll
            for (int k = 0; k < K; ++k) s += prevS[k * SLOTS + tid];
            coord = s;
        }
        acc[tid] = 0.0f;
        if (tid < C) dupf[tid] = 0;
        ((float*)cls)[tid] = coord;
        __syncthreads();

        // ---- phase 1a: center-distance + wave min (threads 0..127)
        //      concurrently: all-pairs coincidence scan (all 256 threads) ----
        const int    di  = tid & (C - 1);
        const float2 dme = cls[di];

        float dcen = 0.0f;
        if (tid < C) {
            const float dxr = dme.x - ((float)tileR + 15.5f);
            const float dyc = dme.y - ((float)tileC + 15.5f);
            dcen = sqrtf(dxr * dxr + dyc * dyc);
            float m = dcen;
#pragma unroll
            for (int off = 32; off > 0; off >>= 1)
                m = fminf(m, __shfl_xor(m, off));
            if ((tid & 63) == 0) waveMin[tid >> 6] = m;
        }

        {
            // pairs (di,(di+k)&127): k=1..32 on waves 0/1, k=33..64 on waves 2/3.
            const int kLo = (tid < C) ? 1 : 33;
#pragma unroll 8
            for (int kk = 0; kk < 32; ++kk) {
                const int k = kLo + kk;
                const int j = (di + k) & (C - 1);
                const float2 o = cls[j];
                if (o.x == dme.x && o.y == dme.y)
                    dupf[(di + k < C) ? (di + k) : di] = 1;  // mark HIGHER index
            }
        }
        __syncthreads();

        // ---- phase 1b: prune + dedup-flag + ballot prefix (order-preserving) ----
        bool keep = false;
        int  pre  = 0;
        if (tid < C) {
            // 2*r_tile = 2*15.5*sqrt(2) = 43.84062; +1.0 clamp/rounding margin
            const float thr = fminf(waveMin[0], waveMin[1]) + 44.84062f;
            keep = (dcen <= thr) && (dupf[tid] == 0);
            const unsigned long long mask = __ballot(keep);
            const int lane = tid & 63;
            pre = __popcll(mask & ((1ull << lane) - 1ull));
            if (lane == 0) waveCnt[tid >> 6] = __popcll(mask);
        }
        __syncthreads();
        if (keep) {
            const int pos = pre + ((tid >= 64) ? waveCnt[0] : 0);
            cand[pos]    = cls[tid];
            candIdx[pos] = tid;
        }
        __syncthreads();

        const int nCand = waveCnt[0] + waveCnt[1];   // >= 1 always

        // ---- phase 2: pruned argmin over candidates ----
        float best[PPT];
        int   bi[PPT];
#pragma unroll
        for (int p = 0; p < PPT; ++p) { best[p] = FLT_MAX; bi[p] = 0; }

        for (int k = 0; k < nCand; ++k) {
            const float2 cl = cand[k];                    // wave-uniform broadcast
            const int    ci = candIdx[k];
            const float  dx  = fr - cl.x;
            const float  dx2 = dx * dx;                   // row-constant, reused x4
#pragma unroll
            for (int p = 0; p < PPT; ++p) {
                const float dy  = colf[p] - cl.y;
                const float d2  = fmaf(dy, dy, dx2);
                const float key = fmaxf(d2, 1.0f);        // clamp before compare
                const bool  lt  = key < best[p];          // strict <: first-index ties
                bi[p]   = lt ? ci  : bi[p];
                best[p] = lt ? key : best[p];
            }
        }

        // ---- epilogue: wave-uniform reduce fast path; LDS scatter ----
#pragma unroll
        for (int p = 0; p < PPT; ++p) {
            const float bd  = fmaxf(1.0f, sqrtf(best[p]));  // = max(1, sqrt(d2))
            const float wgt = hval[p] / bd;
            float v0 = fr      * wgt;
            float v1 = colf[p] * wgt;
            const int b0 = __shfl(bi[p], 0);
            if (__ballot(bi[p] == b0) == 0xFFFFFFFFFFFFFFFFull) {
#pragma unroll
                for (int off = 32; off > 0; off >>= 1) {
                    v0 += __shfl_xor(v0, off);
                    v1 += __shfl_xor(v1, off);
                }
                if ((tid & 63) == 0) {
                    unsafeAtomicAdd(&acc[2 * b0 + 0], v0);
                    unsafeAtomicAdd(&acc[2 * b0 + 1], v1);
                }
            } else {
                unsafeAtomicAdd(&acc[2 * bi[p] + 0], v0);
                unsafeAtomicAdd(&acc[2 * bi[p] + 1], v1);
            }
        }
        __syncthreads();

        // one global atomic per NONZERO slot into this block's shard.
        const float a = acc[tid];
        if (a != 0.0f)
            unsafeAtomicAdd(&outS[(bid & (K - 1)) * SLOTS + tid], a);

        // ---- sharded grid barrier (per-iteration counters, no generations) ----
        __threadfence();                       // drain my atomics device-wide
        __syncthreads();                       // all threads of block fenced
        if (tid == 0) {
            int* cnt = barCnt + ((size_t)it * NCNT + (bid & (NCNT - 1))) * CNT_STRIDE;
            __hip_atomic_fetch_add(cnt, 1, __ATOMIC_RELEASE, __HIP_MEMORY_SCOPE_AGENT);
        }
        const bool lastIter = (it == N_ITER - 1);
        if (!lastIter || bid == 0) {
            if (tid < NCNT) {
                const int* cptr = barCnt + ((size_t)it * NCNT + tid) * CNT_STRIDE;
                while (__hip_atomic_load(cptr, __ATOMIC_ACQUIRE,
                                         __HIP_MEMORY_SCOPE_AGENT) < (NBLK / NCNT))
                    __builtin_amdgcn_s_sleep(1);
            }
            __syncthreads();
        }
    }

    // ---- finalize (block 0 only; it waited on the last barrier) ----
    if (bid == 0) {
        const float* last = shards + (size_t)(N_ITER - 1) * K * SLOTS;
        float s = 0.0f;
#pragma unroll
        for (int k = 0; k < K; ++k) s += last[k * SLOTS + tid];
        out[tid] = s;
    }
}

// ---------------- fallback path (if cooperative launch unavailable) ----------------
__global__ __launch_bounds__(TPB) void kmeans_step(
    const float* __restrict__ cur0,
    const float* __restrict__ prevShards,
    const float* __restrict__ heatmap,
    float* __restrict__ outShards)
{
    __shared__ float2 cls[C];
    __shared__ float2 cand[C];
    __shared__ int    candIdx[C];
    __shared__ float  waveMin[2];
    __shared__ int    waveCnt[2];
    __shared__ float  acc[SLOTS];
    __shared__ unsigned char dupf[C];

    const int tid   = threadIdx.x;
    const int tileR = (blockIdx.x >> 5) * TILE;
    const int tileC = (blockIdx.x & 31) * TILE;

    acc[tid] = 0.0f;
    if (tid < C) dupf[tid] = 0;

    float coord;
    if (prevShards) {
        float s = 0.0f;
#pragma unroll
        for (int k = 0; k < K; ++k) s += prevShards[k * SLOTS + tid];
        coord = s;
    } else {
        coord = cur0[tid];
    }
    ((float*)cls)[tid] = coord;
    __syncthreads();

    const int    di  = tid & (C - 1);
    const float2 dme = cls[di];

    float dcen = 0.0f;
    if (tid < C) {
        const float dxr = dme.x - ((float)tileR + 15.5f);
        const float dyc = dme.y - ((float)tileC + 15.5f);
        dcen = sqrtf(dxr * dxr + dyc * dyc);
        float m = dcen;
#pragma unroll
        for (int off = 32; off > 0; off >>= 1)
            m = fminf(m, __shfl_xor(m, off));
        if ((tid & 63) == 0) waveMin[tid >> 6] = m;
    }
    {
        const int kLo = (tid < C) ? 1 : 33;
#pragma unroll 8
        for (int kk = 0; kk < 32; ++kk) {
            const int k = kLo + kk;
            const int j = (di + k) & (C - 1);
            const float2 o = cls[j];
            if (o.x == dme.x && o.y == dme.y)
                dupf[(di + k < C) ? (di + k) : di] = 1;
        }
    }
    __syncthreads();

    bool keep = false;
    int  pre  = 0;
    if (tid < C) {
        const float thr = fminf(waveMin[0], waveMin[1]) + 44.84062f;
        keep = (dcen <= thr) && (dupf[tid] == 0);
        const unsigned long long mask = __ballot(keep);
        const int lane = tid & 63;
        pre = __popcll(mask & ((1ull << lane) - 1ull));
        if (lane == 0) waveCnt[tid >> 6] = __popcll(mask);
    }
    __syncthreads();
    if (keep) {
        const int pos = pre + ((tid >= 64) ? waveCnt[0] : 0);
        cand[pos]    = cls[tid];
        candIdx[pos] = tid;
    }
    __syncthreads();

    const int nCand = waveCnt[0] + waveCnt[1];

    const int   rowIn = tid >> 3;
    const float fr    = (float)(tileR + rowIn);
    const int   col0  = tileC + (tid & 7) * PPT;
    const float4 h4   = *(const float4*)(heatmap + (size_t)(tileR + rowIn) * W + col0);

    float hval[PPT] = { h4.x, h4.y, h4.z, h4.w };
    float colf[PPT], best[PPT];
    int   bi[PPT];
#pragma unroll
    for (int p = 0; p < PPT; ++p) {
        colf[p] = (float)(col0 + p);
        best[p] = FLT_MAX;
        bi[p]   = 0;
    }

    for (int k = 0; k < nCand; ++k) {
        const float2 cl = cand[k];
        const int    ci = candIdx[k];
        const float  dx  = fr - cl.x;
        const float  dx2 = dx * dx;
#pragma unroll
        for (int p = 0; p < PPT; ++p) {
            const float dy  = colf[p] - cl.y;
            const float d2  = fmaf(dy, dy, dx2);
            const float key = fmaxf(d2, 1.0f);
            const bool  lt  = key < best[p];
            bi[p]   = lt ? ci  : bi[p];
            best[p] = lt ? key : best[p];
        }
    }

#pragma unroll
    for (int p = 0; p < PPT; ++p) {
        const float bd  = fmaxf(1.0f, sqrtf(best[p]));
        const float wgt = hval[p] / bd;
        float v0 = fr      * wgt;
        float v1 = colf[p] * wgt;
        const int b0 = __shfl(bi[p], 0);
        if (__ballot(bi[p] == b0) == 0xFFFFFFFFFFFFFFFFull) {
#pragma unroll
            for (int off = 32; off > 0; off >>= 1) {
                v0 += __shfl_xor(v0, off);
                v1 += __shfl_xor(v1, off);
            }
            if ((tid & 63) == 0) {
                unsafeAtomicAdd(&acc[2 * b0 + 0], v0);
                unsafeAtomicAdd(&acc[2 * b0 + 1], v1);
            }
        } else {
            unsafeAtomicAdd(&acc[2 * bi[p] + 0], v0);
            unsafeAtomicAdd(&acc[2 * bi[p] + 1], v1);
        }
    }
    __syncthreads();

    const float a = acc[tid];
    if (a != 0.0f)
        unsafeAtomicAdd(&outShards[(blockIdx.x & (K - 1)) * SLOTS + tid], a);
}

__global__ __launch_bounds__(SLOTS) void kmeans_finalize(
    const float* __restrict__ shards,
    float* __restrict__ out)
{
    const int tid = threadIdx.x;
    float s = 0.0f;
#pragma unroll
    for (int k = 0; k < K; ++k) s += shards[k * SLOTS + tid];
    out[tid] = s;
}

extern "C" void kernel_launch(void* const* d_in, const int* in_sizes, int n_in,
                              void* d_out, int out_size, void* d_ws, size_t ws_size,
                              hipStream_t stream) {
    const float* clusters = (const float*)d_in[0];  // [C,2] = 256 floats
    const float* heatmap  = (const float*)d_in[1];  // [H,W] = 1M floats
    float* out = (float*)d_out;                     // [C,2] = 256 floats

    // d_ws layout: [N_ITER][K][SLOTS] shard floats, then [N_ITER][NCNT*CNT_STRIDE] ints
    float* shards = (float*)d_ws;                                   // 256 KB
    const size_t shardBytes = (size_t)N_ITER * K * SLOTS * sizeof(float);
    int* barCnt = (int*)((char*)d_ws + shardBytes);                 // 64 KB
    const size_t cntBytes = (size_t)N_ITER * NCNT * CNT_STRIDE * sizeof(int);

    // zero shards + barrier counters (harness re-poisons d_ws before every launch)
    hipMemsetAsync(d_ws, 0, shardBytes + cntBytes, stream);

    void* kargs[] = { (void*)&clusters, (void*)&heatmap, (void*)&shards,
                      (void*)&barCnt,   (void*)&out };
    hipError_t e = hipLaunchCooperativeKernel((const void*)kmeans_fused,
                                              dim3(NBLK), dim3(TPB),
                                              kargs, 0, stream);
    if (e != hipSuccess) {
        (void)hipGetLastError();   // clear sticky error; use multi-dispatch fallback
        const size_t perIter = (size_t)K * SLOTS;
        for (int it = 0; it < N_ITER; ++it) {
            const float* prev = (it == 0) ? nullptr : (shards + (it - 1) * perIter);
            float* dst = shards + it * perIter;
            kmeans_step<<<NBLK, TPB, 0, stream>>>(clusters, prev, heatmap, dst);
        }
        kmeans_finalize<<<1, SLOTS, 0, stream>>>(shards + (N_ITER - 1) * perIter, out);
    }
}